// Round 8
// baseline (463.566 us; speedup 1.0000x reference)
//
#include <hip/hip_runtime.h>

// LSTMP via MFMA, fp32 I/O, f16 compute, fp32 accumulate.
// B=4096, T=512, IN=4, HID=64, PROJ=52.
//
// Round-8: barrier-scheduled ping-pong. One block = 512 thr = 8 waves =
// TWO independent 8-batch groups (G0 waves 0-3, G1 waves 4-7). Per barrier
// interval one group runs the MFMA stage (gates = M@d + [Wih|b]@[x;1],
// M = Whh@Whr precomputed; 12 MFMA) while the other runs the activation
// stage (bpermute-redistributed, 2 units/lane, 20 trans/wave); then swap.
// The block barrier ENFORCES anti-phase so trans (VALU pipe) and MFMA
// (separate pipe, m114) overlap across the two co-resident waves per SIMD.
// Trans floor preserved: 40 trans instr/SIMD/step.
// Recurrent state: d (f16, single-buffer LDS per group - stages are barrier-
// separated so no WAR) + c' = 2L*c (fp32 per-lane). h materialized only in
// the epilogue (Whr @ d_T). log2e folded into M/Wih/b (g rows x2L).
// Numerics identical to R4-R7 -> absmax 9.765625e-4.

#define T_STEPS 512
#define HID 64
#define NPROJ 52
#define ROWB 136            // d-row stride bytes (128B data + 8B pad)
#define GBYTES (16 * ROWB)  // one group's d buffer (batch rows 0-7 live, 8-15 zero)
#define LOG2E 1.44269504088896340736f

typedef _Float16 half8 __attribute__((ext_vector_type(8)));
typedef float f32x4 __attribute__((ext_vector_type(4)));

__device__ __forceinline__ float exp2_f(float x) {
#if __has_builtin(__builtin_amdgcn_exp2f)
    return __builtin_amdgcn_exp2f(x);
#else
    return exp2f(x);
#endif
}
__device__ __forceinline__ float rcp_f(float x) {
    return __builtin_amdgcn_rcpf(x);
}
__device__ __forceinline__ float bperm_f(int addrB, float v) {
    return __int_as_float(__builtin_amdgcn_ds_bpermute(addrB, __float_as_int(v)));
}

__global__ __launch_bounds__(512, 1)
void lstmp_kernel(const float* __restrict__ x,      // [4096][512][4]
                  const float* __restrict__ Wih,    // [256][4]
                  const float* __restrict__ Whh,    // [256][52]
                  const float* __restrict__ bih,    // [256]
                  const float* __restrict__ bhh,    // [256]
                  const float* __restrict__ Whr,    // [52][64]
                  float* __restrict__ out)          // [4096][52]
{
    __shared__ char dlds[2 * GBYTES];    // one d buffer per group

    const int lane = threadIdx.x & 63;
    const int wave = threadIdx.x >> 6;   // 0..7
    const int grp  = wave >> 2;          // group 0/1
    const int gw   = wave & 3;           // gate-row wave within group
    const int quad = lane >> 4;
    const int col  = lane & 15;
    const bool low = (col & 8) == 0;
    const int srcB = (lane & ~8) << 2;   // bpermute byte addr (clear col bit3)

    char* dbase = dlds + grp * GBYTES;

    // ---- zero LDS (d(-1)=0; batch rows 8-15 stay zero forever) ----
    {
        unsigned* p = (unsigned*)dlds;
        for (int i = threadIdx.x; i < (int)(2 * GBYTES / 4); i += 512) p[i] = 0u;
    }

    // ---- one-time: M = Whh @ Whr for this wave's 4 gate tiles (fp32) ----
    const int hid = gw * 16 + col;
    float macc[4][16];
#pragma unroll
    for (int g = 0; g < 4; ++g)
#pragma unroll
        for (int kk = 0; kk < 16; ++kk) macc[g][kk] = 0.0f;

    for (int p = 0; p < NPROJ; ++p) {
        float wv[4];
#pragma unroll
        for (int g = 0; g < 4; ++g) wv[g] = Whh[(g * HID + hid) * NPROJ + p];
        const float* wr = Whr + p * HID + quad * 8;
        const float4 r0 = *(const float4*)(wr);
        const float4 r1 = *(const float4*)(wr + 4);
        const float4 r2 = *(const float4*)(wr + 32);
        const float4 r3 = *(const float4*)(wr + 36);
        const float rk[16] = {r0.x, r0.y, r0.z, r0.w, r1.x, r1.y, r1.z, r1.w,
                              r2.x, r2.y, r2.z, r2.w, r3.x, r3.y, r3.z, r3.w};
#pragma unroll
        for (int g = 0; g < 4; ++g)
#pragma unroll
            for (int kk = 0; kk < 16; ++kk) macc[g][kk] = fmaf(wv[g], rk[kk], macc[g][kk]);
    }

    // ---- fold log2e, convert to f16 A-frags ----
    half8 aM[4][2];    // M-part, K=64
    half8 aXB[4];      // [Wih | bias] part, K=32 (quad0: k<4 = x, k==4 = 1-col)
#pragma unroll
    for (int g = 0; g < 4; ++g) {
        const float scale = (g == 2) ? (2.0f * LOG2E) : LOG2E;
#pragma unroll
        for (int ch = 0; ch < 2; ++ch)
#pragma unroll
            for (int j = 0; j < 8; ++j)
                aM[g][ch][j] = (_Float16)(macc[g][ch * 8 + j] * scale);
        const int row = g * HID + hid;
#pragma unroll
        for (int j = 0; j < 8; ++j) {
            const int k = quad * 8 + j;
            float v = 0.0f;
            if (k < 4)       v = Wih[row * 4 + k];
            else if (k == 4) v = bih[row] + bhh[row];
            aXB[g][j] = (_Float16)(v * scale);
        }
    }

    // ---- x stream (lane's batch = col&7 within its group) ----
    const int gb = blockIdx.x * 16 + grp * 8 + (col & 7);
    const float4* xp = (const float4*)x;
    float4 xcur = xp[(size_t)gb * T_STEPS + 0];
    float4 xv   = xp[(size_t)gb * T_STEPS + 1];
    int xi = 2;                          // index of next x to prefetch

    f32x4 ai = {0.f,0.f,0.f,0.f}, af_ = {0.f,0.f,0.f,0.f};   // gate accs persist
    f32x4 ag_ = {0.f,0.f,0.f,0.f}, ao_ = {0.f,0.f,0.f,0.f};  // across phases
    float cacc[2] = {0.0f, 0.0f};        // c' = 2L*c for this lane's 2 units

    const int dwoff  = (col & 7) * ROWB + (16 * gw + quad * 4 + (low ? 0 : 2)) * 2;
    const int drbase = col * ROWB + quad * 16;

    __syncthreads();   // LDS zeros visible

    // ---- stages ----
    auto mfma_stage = [&]() {
        half8 bx;
#pragma unroll
        for (int j = 0; j < 8; ++j) bx[j] = (_Float16)0.0f;
        if (quad == 0) {
            bx[0] = (_Float16)xcur.x; bx[1] = (_Float16)xcur.y;
            bx[2] = (_Float16)xcur.z; bx[3] = (_Float16)xcur.w;
            bx[4] = (_Float16)1.0f;
        }
        const f32x4 z = {0.f, 0.f, 0.f, 0.f};
        ai  = __builtin_amdgcn_mfma_f32_16x16x32_f16(aXB[0], bx, z, 0, 0, 0);
        af_ = __builtin_amdgcn_mfma_f32_16x16x32_f16(aXB[1], bx, z, 0, 0, 0);
        ag_ = __builtin_amdgcn_mfma_f32_16x16x32_f16(aXB[2], bx, z, 0, 0, 0);
        ao_ = __builtin_amdgcn_mfma_f32_16x16x32_f16(aXB[3], bx, z, 0, 0, 0);

        half8 bd0, bd1;
        {
            const char* p0 = dbase + drbase;
            union { unsigned long long q[2]; half8 h; } u0, u1;
            u0.q[0] = *(const unsigned long long*)(p0);
            u0.q[1] = *(const unsigned long long*)(p0 + 8);
            u1.q[0] = *(const unsigned long long*)(p0 + 64);
            u1.q[1] = *(const unsigned long long*)(p0 + 72);
            bd0 = u0.h; bd1 = u1.h;
        }
        ai  = __builtin_amdgcn_mfma_f32_16x16x32_f16(aM[0][0], bd0, ai,  0, 0, 0);
        af_ = __builtin_amdgcn_mfma_f32_16x16x32_f16(aM[1][0], bd0, af_, 0, 0, 0);
        ag_ = __builtin_amdgcn_mfma_f32_16x16x32_f16(aM[2][0], bd0, ag_, 0, 0, 0);
        ao_ = __builtin_amdgcn_mfma_f32_16x16x32_f16(aM[3][0], bd0, ao_, 0, 0, 0);
        ai  = __builtin_amdgcn_mfma_f32_16x16x32_f16(aM[0][1], bd1, ai,  0, 0, 0);
        af_ = __builtin_amdgcn_mfma_f32_16x16x32_f16(aM[1][1], bd1, af_, 0, 0, 0);
        ag_ = __builtin_amdgcn_mfma_f32_16x16x32_f16(aM[2][1], bd1, ag_, 0, 0, 0);
        ao_ = __builtin_amdgcn_mfma_f32_16x16x32_f16(aM[3][1], bd1, ao_, 0, 0, 0);

        xcur = xv;
        const int tn = (xi < T_STEPS) ? xi : (T_STEPS - 1);
        xv = xp[(size_t)gb * T_STEPS + tn];
        ++xi;
    };

    auto act_stage = [&]() {
        // redistribute: lanes col>=8 take rows r={2,3} of batch col-8
        float yi[2], yf[2], yg[2], yo[2];
        {
            const float ti2 = bperm_f(srcB, ai[2]),  ti3 = bperm_f(srcB, ai[3]);
            const float tf2 = bperm_f(srcB, af_[2]), tf3 = bperm_f(srcB, af_[3]);
            const float tg2 = bperm_f(srcB, ag_[2]), tg3 = bperm_f(srcB, ag_[3]);
            const float to2 = bperm_f(srcB, ao_[2]), to3 = bperm_f(srcB, ao_[3]);
            yi[0] = low ? ai[0]  : ti2;  yi[1] = low ? ai[1]  : ti3;
            yf[0] = low ? af_[0] : tf2;  yf[1] = low ? af_[1] : tf3;
            yg[0] = low ? ag_[0] : tg2;  yg[1] = low ? ag_[1] : tg3;
            yo[0] = low ? ao_[0] : to2;  yo[1] = low ? ao_[1] : to3;
        }
        union { _Float16 h[2]; unsigned w; } du;
#pragma unroll
        for (int u = 0; u < 2; ++u) {
            const float iv = rcp_f(1.0f + exp2_f(-yi[u]));                   // sigmoid
            const float fv = rcp_f(1.0f + exp2_f(-yf[u]));
            const float ov = rcp_f(1.0f + exp2_f(-yo[u]));
            const float gs = fmaf(-4.0f * LOG2E, rcp_f(1.0f + exp2_f(yg[u])),
                                  2.0f * LOG2E);                             // 2L*tanh(g)
            const float cn = fmaf(fv, cacc[u], iv * gs);                     // c' = 2L*c
            cacc[u] = cn;
            const float th = fmaf(-2.0f, rcp_f(1.0f + exp2_f(cn)), 1.0f);    // tanh(c)
            du.h[u] = (_Float16)(ov * th);                                   // RTNE
        }
        *(unsigned*)(dbase + dwoff) = du.w;
    };

    // ---- ping-pong recurrence: G1 runs half a step ahead in MFMA ----
    if (grp == 1) mfma_stage();          // G1: gates(0) from d(-1)=0
    __syncthreads();

#pragma unroll 1
    for (int t = 0; t < T_STEPS; ++t) {
        if (grp == 0) mfma_stage(); else act_stage();   // G0 gates(t) | G1 d(t)
        __syncthreads();
        if (grp == 0) act_stage(); else mfma_stage();   // G0 d(t) | G1 gates(t+1)
        __syncthreads();
    }
    // (G1's final mfma_stage(512) is harmless: registers only)

    // ---- epilogue: h_T = Whr @ d(511) per group ----
    half8 aP[2];
    const int prow = gw * 16 + col;
#pragma unroll
    for (int ch = 0; ch < 2; ++ch)
#pragma unroll
        for (int j = 0; j < 8; ++j) {
            const int k = ch * 32 + quad * 8 + j;
            aP[ch][j] = (_Float16)((prow < NPROJ) ? Whr[prow * HID + k] : 0.0f);
        }

    half8 bd0, bd1;
    {
        const char* p0 = dbase + drbase;
        union { unsigned long long q[2]; half8 h; } u0, u1;
        u0.q[0] = *(const unsigned long long*)(p0);
        u0.q[1] = *(const unsigned long long*)(p0 + 8);
        u1.q[0] = *(const unsigned long long*)(p0 + 64);
        u1.q[1] = *(const unsigned long long*)(p0 + 72);
        bd0 = u0.h; bd1 = u1.h;
    }
    f32x4 hf = {0.f, 0.f, 0.f, 0.f};
    hf = __builtin_amdgcn_mfma_f32_16x16x32_f16(aP[0], bd0, hf, 0, 0, 0);
    hf = __builtin_amdgcn_mfma_f32_16x16x32_f16(aP[1], bd1, hf, 0, 0, 0);

    // store: p = gw*16 + quad*4 + r, batch = gb (cols 0-7 only)
    if (col < 8) {
        float* o = out + (size_t)gb * NPROJ;
        const int p0 = gw * 16 + quad * 4;
#pragma unroll
        for (int r = 0; r < 4; ++r) {
            const int p = p0 + r;
            if (p < NPROJ) o[p] = hf[r];
        }
    }
}

extern "C" void kernel_launch(void* const* d_in, const int* in_sizes, int n_in,
                              void* d_out, int out_size, void* d_ws, size_t ws_size,
                              hipStream_t stream) {
    const float* x   = (const float*)d_in[0];
    const float* Wih = (const float*)d_in[1];
    const float* Whh = (const float*)d_in[2];
    const float* bih = (const float*)d_in[3];
    const float* bhh = (const float*)d_in[4];
    const float* Whr = (const float*)d_in[5];
    float* out = (float*)d_out;

    dim3 grid(256);    // 16 batches per block (2 groups of 8), 1 block per CU
    dim3 block(512);   // 8 waves = 2 waves/SIMD (one per group)
    lstmp_kernel<<<grid, block, 0, stream>>>(x, Wih, Whh, bih, bhh, Whr, out);
}

// Round 9
// 314.644 us; speedup vs baseline: 1.4733x; 1.4733x over previous
//
#include <hip/hip_runtime.h>

// LSTMP via MFMA, fp32 I/O, f16 compute, fp32 accumulate.
// B=4096, T=512, IN=4, HID=64, PROJ=52. Grid 256 x 256thr (4 waves), 16 batch/block.
//
// Round-9 = Round-7 + NO GLOBAL LOADS IN THE LOOP.
// R7/R8 post-mortem: the compiler emits s_waitcnt vmcnt(0) before every
// s_barrier, so the in-loop global x-prefetch exposed ~400+ cyc of HBM/L3
// latency at each step's barrier. Fix: stage the block's whole x slab into
// LDS once (f16, [t][b] 8B cells, 64 KB) -> steady loop is LDS-only and the
// barrier drain is lgkmcnt-only. Loop body is reads-first so LDS latency
// hides under the MFMA block.
//   gates = (Whh@Whr)*d + [Wih|b]@[x;1]   (M precomputed per block, fp32)
//   12 MFMA + 40-trans activations + d write + ONE barrier per step.
// log2e folded (i,f,o rows xL; g rows x2L; c'=2L*c); RTNE f16 d.
// Numerics bit-identical to R7 -> absmax 9.765625e-4.

#define T_STEPS 512
#define HID 64
#define NPROJ 52
#define NBATCH 16
#define ROWB 136
#define DBYTES (NBATCH * ROWB)     // 2176 B per d buffer
#define XBYTES (T_STEPS * 128)     // 65536 B: x_lds[t][b] 8B cells (4 x f16)
#define LOG2E 1.44269504088896340736f

typedef _Float16 half8 __attribute__((ext_vector_type(8)));
typedef float f32x4 __attribute__((ext_vector_type(4)));

__device__ __forceinline__ float exp2_f(float x) {
#if __has_builtin(__builtin_amdgcn_exp2f)
    return __builtin_amdgcn_exp2f(x);
#else
    return exp2f(x);
#endif
}
__device__ __forceinline__ float rcp_f(float x) {
    return __builtin_amdgcn_rcpf(x);
}

__global__ __launch_bounds__(256, 1)
void lstmp_kernel(const float* __restrict__ x,      // [4096][512][4]
                  const float* __restrict__ Wih,    // [256][4]
                  const float* __restrict__ Whh,    // [256][52]
                  const float* __restrict__ bih,    // [256]
                  const float* __restrict__ bhh,    // [256]
                  const float* __restrict__ Whr,    // [52][64]
                  float* __restrict__ out)          // [4096][52]
{
    __shared__ char lds[XBYTES + 2 * DBYTES];
    char* xl = lds;                 // x_lds: [t][b] 8B cells, banks conflict-free on read
    char* dl = lds + XBYTES;        // double-buffered d, [16 batch][136B]

    const int lane = threadIdx.x & 63;
    const int wave = threadIdx.x >> 6;   // 0..3
    const int quad = lane >> 4;
    const int col  = lane & 15;          // batch (B/C col), row-in-tile (A)

    // ---- zero d buffers (t=0 reads buffer 0 as d(-1)=0) ----
    {
        unsigned* p = (unsigned*)dl;
        for (int i = threadIdx.x; i < (int)(2 * DBYTES / 4); i += 256) p[i] = 0u;
    }

    // ---- stage x -> LDS as f16 (one-time; coalesced global reads) ----
    {
        const float4* xg = (const float4*)x + (size_t)blockIdx.x * NBATCH * T_STEPS;
        for (int i = threadIdx.x; i < NBATCH * T_STEPS; i += 256) {
            const int b = i >> 9;          // global layout is b-major
            const int t = i & (T_STEPS - 1);
            const float4 v = xg[i];
            union { _Float16 h[4]; unsigned long long q; } u;
            u.h[0] = (_Float16)v.x; u.h[1] = (_Float16)v.y;
            u.h[2] = (_Float16)v.z; u.h[3] = (_Float16)v.w;
            *(unsigned long long*)(xl + t * 128 + b * 8) = u.q;
        }
    }

    // ---- one-time: M = Whh @ Whr for this wave's 4 gate tiles (fp32) ----
    const int hid = wave * 16 + col;
    float macc[4][16];
#pragma unroll
    for (int g = 0; g < 4; ++g)
#pragma unroll
        for (int kk = 0; kk < 16; ++kk) macc[g][kk] = 0.0f;

    for (int p = 0; p < NPROJ; ++p) {
        float wv[4];
#pragma unroll
        for (int g = 0; g < 4; ++g) wv[g] = Whh[(g * HID + hid) * NPROJ + p];
        const float* wr = Whr + p * HID + quad * 8;
        const float4 r0 = *(const float4*)(wr);
        const float4 r1 = *(const float4*)(wr + 4);
        const float4 r2 = *(const float4*)(wr + 32);
        const float4 r3 = *(const float4*)(wr + 36);
        const float rk[16] = {r0.x, r0.y, r0.z, r0.w, r1.x, r1.y, r1.z, r1.w,
                              r2.x, r2.y, r2.z, r2.w, r3.x, r3.y, r3.z, r3.w};
#pragma unroll
        for (int g = 0; g < 4; ++g)
#pragma unroll
            for (int kk = 0; kk < 16; ++kk) macc[g][kk] = fmaf(wv[g], rk[kk], macc[g][kk]);
    }

    // ---- fold log2e, convert to f16 A-frags ----
    half8 aM[4][2];    // M-part, K=64
    half8 aXB[4];      // [Wih | bias] part, K=32 (quad0: k<4 = x, k==4 = 1-col)
#pragma unroll
    for (int g = 0; g < 4; ++g) {
        const float scale = (g == 2) ? (2.0f * LOG2E) : LOG2E;
#pragma unroll
        for (int ch = 0; ch < 2; ++ch)
#pragma unroll
            for (int j = 0; j < 8; ++j)
                aM[g][ch][j] = (_Float16)(macc[g][ch * 8 + j] * scale);
        const int row = g * HID + hid;
#pragma unroll
        for (int j = 0; j < 8; ++j) {
            const int k = quad * 8 + j;
            float v = 0.0f;
            if (k < 4)       v = Wih[row * 4 + k];
            else if (k == 4) v = bih[row] + bhh[row];
            aXB[g][j] = (_Float16)(v * scale);
        }
    }

    float cacc[4] = {0.0f, 0.0f, 0.0f, 0.0f};           // c' = 2L*c, hid = 16w+quad*4+r

    const int dwoff  = col * ROWB + wave * 32 + quad * 8;  // d write (b64)
    const int drbase = col * ROWB + quad * 16;             // d read base (+ch*64)
    const char* xrd  = xl + col * 8;                       // + t*128 per step

    __syncthreads();   // staging + zeros visible

#pragma unroll 1
    for (int t = 0; t < T_STEPS; ++t) {
        const char* rbuf = dl + (t & 1) * DBYTES;
        char* wbuf = dl + ((t + 1) & 1) * DBYTES;

        // ---- reads first: d(t-1) B-frags + x(t) cell (LDS latency hides under MFMA) ----
        half8 bd0, bd1;
        {
            const char* p0 = rbuf + drbase;
            union { unsigned long long q[2]; half8 h; } u0, u1;
            u0.q[0] = *(const unsigned long long*)(p0);
            u0.q[1] = *(const unsigned long long*)(p0 + 8);
            u1.q[0] = *(const unsigned long long*)(p0 + 64);
            u1.q[1] = *(const unsigned long long*)(p0 + 72);
            bd0 = u0.h; bd1 = u1.h;
        }
        half8 bx;
#pragma unroll
        for (int j = 0; j < 8; ++j) bx[j] = (_Float16)0.0f;
        if (quad == 0) {
            union { unsigned long long q; _Float16 h[4]; } u;
            u.q = *(const unsigned long long*)(xrd + t * 128);
            bx[0] = u.h[0]; bx[1] = u.h[1]; bx[2] = u.h[2]; bx[3] = u.h[3];
            bx[4] = (_Float16)1.0f;
        }

        // ---- gates: 4 xb-MFMA (K=32 seed) + 8 M-MFMA (K=64) ----
        const f32x4 z = {0.f, 0.f, 0.f, 0.f};
        f32x4 ai, af_, ag_, ao_;
        ai  = __builtin_amdgcn_mfma_f32_16x16x32_f16(aXB[0], bx, z, 0, 0, 0);
        af_ = __builtin_amdgcn_mfma_f32_16x16x32_f16(aXB[1], bx, z, 0, 0, 0);
        ag_ = __builtin_amdgcn_mfma_f32_16x16x32_f16(aXB[2], bx, z, 0, 0, 0);
        ao_ = __builtin_amdgcn_mfma_f32_16x16x32_f16(aXB[3], bx, ao_ = z, 0, 0, 0);
        ai  = __builtin_amdgcn_mfma_f32_16x16x32_f16(aM[0][0], bd0, ai,  0, 0, 0);
        af_ = __builtin_amdgcn_mfma_f32_16x16x32_f16(aM[1][0], bd0, af_, 0, 0, 0);
        ag_ = __builtin_amdgcn_mfma_f32_16x16x32_f16(aM[2][0], bd0, ag_, 0, 0, 0);
        ao_ = __builtin_amdgcn_mfma_f32_16x16x32_f16(aM[3][0], bd0, ao_, 0, 0, 0);
        ai  = __builtin_amdgcn_mfma_f32_16x16x32_f16(aM[0][1], bd1, ai,  0, 0, 0);
        af_ = __builtin_amdgcn_mfma_f32_16x16x32_f16(aM[1][1], bd1, af_, 0, 0, 0);
        ag_ = __builtin_amdgcn_mfma_f32_16x16x32_f16(aM[2][1], bd1, ag_, 0, 0, 0);
        ao_ = __builtin_amdgcn_mfma_f32_16x16x32_f16(aM[3][1], bd1, ao_, 0, 0, 0);

        // ---- activations + cell update (per-lane; hid = 16w + quad*4 + r) ----
        union { _Float16 h[4]; unsigned long long q; } du;
#pragma unroll
        for (int r = 0; r < 4; ++r) {
            const float iv = rcp_f(1.0f + exp2_f(-ai[r]));                       // sigmoid
            const float fv = rcp_f(1.0f + exp2_f(-af_[r]));
            const float ov = rcp_f(1.0f + exp2_f(-ao_[r]));
            const float gs = fmaf(-4.0f * LOG2E, rcp_f(1.0f + exp2_f(ag_[r])),
                                  2.0f * LOG2E);                                 // 2L*tanh(g)
            const float cn = fmaf(fv, cacc[r], iv * gs);                         // c' = 2L*c
            cacc[r] = cn;
            const float th = fmaf(-2.0f, rcp_f(1.0f + exp2_f(cn)), 1.0f);        // tanh(c)
            du.h[r] = (_Float16)(ov * th);                                       // RTNE
        }
        *(unsigned long long*)(wbuf + dwoff) = du.q;

        __syncthreads();   // the ONLY barrier per step; lgkmcnt-only drain now
    }

    // ---- epilogue: h_T = Whr @ d(511); d(511) is in buffer 0 ----
    half8 aP[2];
    const int prow = wave * 16 + col;
#pragma unroll
    for (int ch = 0; ch < 2; ++ch)
#pragma unroll
        for (int j = 0; j < 8; ++j) {
            const int k = ch * 32 + quad * 8 + j;
            aP[ch][j] = (_Float16)((prow < NPROJ) ? Whr[prow * HID + k] : 0.0f);
        }

    half8 bd0, bd1;
    {
        const char* p0 = dl + 0 * DBYTES + drbase;
        union { unsigned long long q[2]; half8 h; } u0, u1;
        u0.q[0] = *(const unsigned long long*)(p0);
        u0.q[1] = *(const unsigned long long*)(p0 + 8);
        u1.q[0] = *(const unsigned long long*)(p0 + 64);
        u1.q[1] = *(const unsigned long long*)(p0 + 72);
        bd0 = u0.h; bd1 = u1.h;
    }
    f32x4 hf = {0.f, 0.f, 0.f, 0.f};
    hf = __builtin_amdgcn_mfma_f32_16x16x32_f16(aP[0], bd0, hf, 0, 0, 0);
    hf = __builtin_amdgcn_mfma_f32_16x16x32_f16(aP[1], bd1, hf, 0, 0, 0);

    // store: p = wave*16 + quad*4 + r, batch = col  (wave 3: only quad 0 valid)
    const size_t bg = (size_t)blockIdx.x * NBATCH + col;
    float* o = out + bg * NPROJ;
    const int p0 = wave * 16 + quad * 4;
#pragma unroll
    for (int r = 0; r < 4; ++r) {
        const int p = p0 + r;
        if (p < NPROJ) o[p] = hf[r];
    }
}

extern "C" void kernel_launch(void* const* d_in, const int* in_sizes, int n_in,
                              void* d_out, int out_size, void* d_ws, size_t ws_size,
                              hipStream_t stream) {
    const float* x   = (const float*)d_in[0];
    const float* Wih = (const float*)d_in[1];
    const float* Whh = (const float*)d_in[2];
    const float* bih = (const float*)d_in[3];
    const float* bhh = (const float*)d_in[4];
    const float* Whr = (const float*)d_in[5];
    float* out = (float*)d_out;

    dim3 grid(4096 / NBATCH);   // 256 blocks, 1 per CU
    dim3 block(256);            // 4 waves, 1 wave/SIMD
    lstmp_kernel<<<grid, block, 0, stream>>>(x, Wih, Whh, bih, bhh, Whr, out);
}